// Round 7
// baseline (184.759 us; speedup 1.0000x reference)
//
#include <hip/hip_runtime.h>
#include <hip/hip_bf16.h>

#define B_  2
#define S_  2048
#define D_  1024
#define H_  16
#define DH_ 64
#define M_  (B_ * S_)       // 4096
#define QKV_LD (3 * D_)     // 3072

typedef __bf16 bf16x8 __attribute__((ext_vector_type(8)));
typedef float  f32x4  __attribute__((ext_vector_type(4)));
typedef unsigned short us4 __attribute__((ext_vector_type(4)));
typedef unsigned short us8 __attribute__((ext_vector_type(8)));

__device__ inline unsigned short f2bf(float f) {
  union { __bf16 h; unsigned short u; } cv; cv.h = (__bf16)f; return cv.u;
}
__device__ inline float bf2f(unsigned short u) {
  union { unsigned int i; float f; } cv; cv.i = ((unsigned int)u) << 16; return cv.f;
}
// typed stores: bf16 does the BIT conversion (round-3 bug: (unsigned short)v
// was an int conversion -> output was all-zero)
__device__ inline void cstore(float* p, float v) { *p = v; }
__device__ inline void cstore(unsigned short* p, float v) { *p = f2bf(v); }

__device__ inline void gload_lds16(const void* g, void* lds) {
  __builtin_amdgcn_global_load_lds(
      (const __attribute__((address_space(1))) unsigned int*)g,
      (__attribute__((address_space(3))) unsigned int*)lds, 16, 0, 0);
}

// ---------------- prep: fp32 -> bf16 (row-major copy) ----------------
__global__ __launch_bounds__(256) void conv_bf16(const float* __restrict__ in,
                                                 unsigned short* __restrict__ out, int n4) {
  int i = blockIdx.x * 256 + threadIdx.x;
  if (i >= n4) return;
  float4 v = ((const float4*)in)[i];
  us4 p = { f2bf(v.x), f2bf(v.y), f2bf(v.z), f2bf(v.w) };
  ((us4*)out)[i] = p;
}

// ---------------- prep: fp32 [K][N] -> bf16 [N][K] transpose ----------------
__global__ __launch_bounds__(256) void transpose_bf16(const float* __restrict__ W,
                                                      unsigned short* __restrict__ Wt,
                                                      int K, int N) {
  __shared__ float tile[32][33];
  const int t = threadIdx.x, tx = t & 31, ty = t >> 5;  // ty 0..7
  const int c0 = blockIdx.x * 32, r0 = blockIdx.y * 32;
  #pragma unroll
  for (int i = 0; i < 4; ++i)
    tile[ty + 8 * i][tx] = W[(size_t)(r0 + ty + 8 * i) * N + c0 + tx];
  __syncthreads();
  #pragma unroll
  for (int i = 0; i < 4; ++i)
    Wt[(size_t)(c0 + ty + 8 * i) * K + r0 + tx] = f2bf(tile[tx][ty + 8 * i]);
}

// ---------------- bf16 MFMA GEMM (m97 structure) ----------------
// C[M,N] = A[M,K] @ Bt[N,K]^T + bias.  128x128 tile, BK=32, 4 waves.
template<typename CT>
__global__ __launch_bounds__(256) void gemm_bf16_tn(
    const unsigned short* __restrict__ A,   // [M][K] bf16
    const unsigned short* __restrict__ Bt,  // [N][K] bf16
    const float* __restrict__ bias,
    CT* __restrict__ C, int N, int K) {
  __shared__ __align__(16) unsigned short smA[128 * 32];
  __shared__ __align__(16) unsigned short smB[128 * 32];
  const int t = threadIdx.x;
  const int w = t >> 6, l = t & 63;
  const int lg = l >> 4, lr = l & 15;
  const int row0 = blockIdx.y * 128, col0 = blockIdx.x * 128;
  const int wm = (w >> 1) * 64, wn = (w & 1) * 64;

  f32x4 acc[4][4] = {};

  for (int k0 = 0; k0 < K; k0 += 32) {
    __syncthreads();  // previous iteration's fragment reads complete
    #pragma unroll
    for (int i = 0; i < 2; ++i) {
      const int inst = 2 * w + i;
      const int r = inst * 16 + (l >> 2);
      const int cb = (l & 3) * 8;  // k-chunk of 8 bf16
      gload_lds16(A  + (size_t)(row0 + r) * K + k0 + cb, &smA[inst * 512]);
      gload_lds16(Bt + (size_t)(col0 + r) * K + k0 + cb, &smB[inst * 512]);
    }
    __syncthreads();  // waits vmcnt(0): tiles resident

    bf16x8 af[4], bfr[4];
    #pragma unroll
    for (int m = 0; m < 4; ++m)
      af[m] = *(const bf16x8*)&smA[(wm + m * 16 + lr) * 32 + lg * 8];
    #pragma unroll
    for (int n = 0; n < 4; ++n)
      bfr[n] = *(const bf16x8*)&smB[(wn + n * 16 + lr) * 32 + lg * 8];
    #pragma unroll
    for (int m = 0; m < 4; ++m)
      #pragma unroll
      for (int n = 0; n < 4; ++n)
        acc[m][n] = __builtin_amdgcn_mfma_f32_16x16x32_bf16(af[m], bfr[n], acc[m][n], 0, 0, 0);
  }

  #pragma unroll
  for (int m = 0; m < 4; ++m) {
    #pragma unroll
    for (int n = 0; n < 4; ++n) {
      const int col = col0 + wn + n * 16 + lr;
      const float bv = bias[col];
      #pragma unroll
      for (int r = 0; r < 4; ++r) {
        const int row = row0 + wm + m * 16 + lg * 4 + r;
        cstore(&C[(size_t)row * N + col], acc[m][n][r] + bv);
      }
    }
  }
}

// ---------------- Causal flash attention, bf16 MFMA ----------------
// Block x owns q-tiles lo=x and hi=31-x (64 rows each, 4 waves x 16 rows).
// ONE k-loop over tiles 0..31-x stages K/V ONCE; hi consumes every tile,
// lo only while kti <= x (scalar-uniform). Compute = 33 units/block
// (balanced); staging/barriers = 32-x (avg 24.5). K/V fragments shared
// between the two q-tiles. LDS dbuf + T14 async staging, s_setprio on MFMA.
__global__ __launch_bounds__(256) void attn_fwd_mfma(
    const unsigned short* __restrict__ qkv, unsigned short* __restrict__ attn_out) {
  const int bh = blockIdx.y;
  const int b = bh / H_, h = bh % H_;
  const unsigned short* base = qkv + (size_t)b * S_ * QKV_LD;

  __shared__ __align__(16) char smK[2][64 * 128];  // K tile [k][d], XOR-swizzled
  __shared__ __align__(16) char smV[2][64 * 128];  // V^T tile [d][k]
  __shared__ __align__(16) char smP[128 * 128];    // P rows: lo 0..63, hi 64..127

  const int t  = threadIdx.x;
  const int w  = t >> 6;
  const int l  = t & 63;
  const int lg = l >> 4;
  const int lr = l & 15;

  const int x   = blockIdx.x;       // lo q-tile index
  const int qlo0 = 64 * x + w * 16;
  const int qhi0 = 64 * (31 - x) + w * 16;

  const unsigned short* kbase = base + D_ + h * DH_;
  const unsigned short* vbase = base + 2 * D_ + h * DH_;

  // ---- Q fragments (pre-scaled by 1/8) for both q-tiles ----
  bf16x8 qflo[2], qfhi[2];
  #pragma unroll
  for (int p = 0; p < 2; ++p) {
    const int qr = (p ? qhi0 : qlo0) + lr;
    const unsigned short* qp = base + (size_t)qr * QKV_LD + h * DH_ + 8 * lg;
    #pragma unroll
    for (int ks = 0; ks < 2; ++ks) {
      us8 qv = *(const us8*)(qp + 32 * ks);
      #pragma unroll
      for (int e = 0; e < 8; ++e)
        (p ? qfhi : qflo)[ks][e] = (__bf16)(bf2f(qv[e]) * 0.125f);
    }
  }

  float mlo[4], llo[4], mhi[4], lhi[4];
  f32x4 alo[4] = {}, ahi[4] = {};
  #pragma unroll
  for (int r = 0; r < 4; ++r) { mlo[r] = mhi[r] = -1e30f; llo[r] = lhi[r] = 0.f; }

  // staging registers (T14 async split: issue early, LDS-write late)
  us8 kreg[2], vreg[2];
  const int kp  = (t & 31) * 2;    // V: pair of k-columns
  const int vdb = (t >> 5) * 8;    // V: 8 d-rows

  auto issue_loads = [&](int k0) {
    #pragma unroll
    for (int it = 0; it < 2; ++it) {
      int idx = t + it * 256;
      int r = idx >> 3, c = idx & 7;
      kreg[it] = *(const us8*)(kbase + (size_t)(k0 + r) * QKV_LD + c * 8);
    }
    vreg[0] = *(const us8*)(vbase + (size_t)(k0 + kp) * QKV_LD + vdb);
    vreg[1] = *(const us8*)(vbase + (size_t)(k0 + kp + 1) * QKV_LD + vdb);
  };
  auto write_lds = [&](int buf) {
    #pragma unroll
    for (int it = 0; it < 2; ++it) {
      int idx = t + it * 256;
      int r = idx >> 3, c = idx & 7;
      *(us8*)(smK[buf] + r * 128 + ((c * 16) ^ ((r & 7) << 4))) = kreg[it];
    }
    #pragma unroll
    for (int j = 0; j < 8; ++j) {
      int row = vdb + j;
      unsigned int pv = (unsigned int)vreg[0][j] | ((unsigned int)vreg[1][j] << 16);
      *(unsigned int*)(smV[buf] + row * 128 + ((2 * kp) ^ ((row & 7) << 4))) = pv;
    }
  };

  // softmax+P-write+rescale for one q-tile (sc consumed; pa returned)
  auto finish_part = [&](f32x4 (&sc)[4], float (&mrun)[4], float (&lrun)[4],
                         f32x4 (&acc)[4], bf16x8 (&pa)[2],
                         int qp0, int prow0, int k0, bool domask) {
    if (domask) {
      #pragma unroll
      for (int kt = 0; kt < 4; ++kt) {
        int kc = k0 + kt * 16 + lr;
        #pragma unroll
        for (int r = 0; r < 4; ++r)
          if (kc > qp0 + lg * 4 + r) sc[kt][r] = -1e30f;
      }
    }
    float mnew[4], alpha[4];
    #pragma unroll
    for (int r = 0; r < 4; ++r) {
      float v = fmaxf(fmaxf(sc[0][r], sc[1][r]), fmaxf(sc[2][r], sc[3][r]));
      #pragma unroll
      for (int off = 1; off < 16; off <<= 1) v = fmaxf(v, __shfl_xor(v, off));
      mnew[r] = fmaxf(mrun[r], v);
      alpha[r] = __expf(mrun[r] - mnew[r]);
      mrun[r] = mnew[r];
    }
    #pragma unroll
    for (int r = 0; r < 4; ++r) {
      float s = 0.f;
      #pragma unroll
      for (int kt = 0; kt < 4; ++kt) {
        float p = __expf(sc[kt][r] - mnew[r]);
        sc[kt][r] = p;
        s += p;
      }
      #pragma unroll
      for (int off = 1; off < 16; off <<= 1) s += __shfl_xor(s, off);
      lrun[r] = lrun[r] * alpha[r] + s;
    }
    #pragma unroll
    for (int kt = 0; kt < 4; ++kt)
      #pragma unroll
      for (int r = 0; r < 4; ++r) {
        int row = prow0 + lg * 4 + r;
        *(unsigned short*)(smP + row * 128 + ((2 * (kt * 16 + lr)) ^ ((row & 7) << 4))) =
            f2bf(sc[kt][r]);
      }
    #pragma unroll
    for (int dt = 0; dt < 4; ++dt)
      #pragma unroll
      for (int r = 0; r < 4; ++r) acc[dt][r] *= alpha[r];
    #pragma unroll
    for (int ks = 0; ks < 2; ++ks) {
      int row = prow0 + lr;
      pa[ks] = *(const bf16x8*)(smP + row * 128 +
                                (((ks * 64) + 16 * lg) ^ ((lr & 7) << 4)));
    }
  };

  const int ntiles = 32 - x;   // k-tiles for hi (superset of lo's 0..x)
  issue_loads(0);
  write_lds(0);
  __syncthreads();

  for (int kti = 0; kti < ntiles; ++kti) {
    const int k0 = kti * 64;
    const int cur = kti & 1;
    const bool lo_act = (kti <= x);

    if (kti + 1 < ntiles) issue_loads((kti + 1) * 64);

    // ---- K fragments, loaded once, shared by both q-tiles ----
    bf16x8 kb[4][2];
    #pragma unroll
    for (int kt = 0; kt < 4; ++kt)
      #pragma unroll
      for (int ks = 0; ks < 2; ++ks) {
        int row = kt * 16 + lr;
        kb[kt][ks] = *(const bf16x8*)(smK[cur] + row * 128 +
                                      (((ks * 64) + 16 * lg) ^ ((row & 7) << 4)));
      }

    // ---- hi QK^T (always active) ----
    f32x4 schi[4] = {};
    __builtin_amdgcn_s_setprio(1);
    #pragma unroll
    for (int kt = 0; kt < 4; ++kt)
      #pragma unroll
      for (int ks = 0; ks < 2; ++ks)
        schi[kt] = __builtin_amdgcn_mfma_f32_16x16x32_bf16(qfhi[ks], kb[kt][ks], schi[kt], 0, 0, 0);
    __builtin_amdgcn_s_setprio(0);

    bf16x8 pa_hi[2], pa_lo[2];
    finish_part(schi, mhi, lhi, ahi, pa_hi, qhi0, 64 + w * 16, k0,
                kti == ntiles - 1);

    if (lo_act) {
      f32x4 sclo[4] = {};
      __builtin_amdgcn_s_setprio(1);
      #pragma unroll
      for (int kt = 0; kt < 4; ++kt)
        #pragma unroll
        for (int ks = 0; ks < 2; ++ks)
          sclo[kt] = __builtin_amdgcn_mfma_f32_16x16x32_bf16(qflo[ks], kb[kt][ks], sclo[kt], 0, 0, 0);
      __builtin_amdgcn_s_setprio(0);
      finish_part(sclo, mlo, llo, alo, pa_lo, qlo0, w * 16, k0, kti == x);
    }

    // ---- PV: V fragments loaded once, shared ----
    __builtin_amdgcn_s_setprio(1);
    #pragma unroll
    for (int dt = 0; dt < 4; ++dt)
      #pragma unroll
      for (int ks = 0; ks < 2; ++ks) {
        int row = dt * 16 + lr;
        bf16x8 vb = *(const bf16x8*)(smV[cur] + row * 128 +
                                     (((ks * 64) + 16 * lg) ^ ((row & 7) << 4)));
        ahi[dt] = __builtin_amdgcn_mfma_f32_16x16x32_bf16(pa_hi[ks], vb, ahi[dt], 0, 0, 0);
        if (lo_act)
          alo[dt] = __builtin_amdgcn_mfma_f32_16x16x32_bf16(pa_lo[ks], vb, alo[dt], 0, 0, 0);
      }
    __builtin_amdgcn_s_setprio(0);

    if (kti + 1 < ntiles) write_lds(cur ^ 1);  // buf cur^1 free since last barrier
    __syncthreads();
  }

  // ---- normalize and write out (bf16), both q-tiles ----
  #pragma unroll
  for (int p = 0; p < 2; ++p) {
    const int q0 = p ? qhi0 : qlo0;
    float inv[4];
    #pragma unroll
    for (int r = 0; r < 4; ++r) inv[r] = 1.0f / (p ? lhi : llo)[r];
    #pragma unroll
    for (int dt = 0; dt < 4; ++dt)
      #pragma unroll
      for (int r = 0; r < 4; ++r) {
        float v = (p ? ahi : alo)[dt][r] * inv[r];
        attn_out[(size_t)(b * S_ + q0 + lg * 4 + r) * D_ + h * DH_ + dt * 16 + lr] = f2bf(v);
      }
  }
}

extern "C" void kernel_launch(void* const* d_in, const int* in_sizes, int n_in,
                              void* d_out, int out_size, void* d_ws, size_t ws_size,
                              hipStream_t stream) {
  const float* x     = (const float*)d_in[0];
  const float* W_qkv = (const float*)d_in[1];
  const float* b_qkv = (const float*)d_in[2];
  const float* W_out = (const float*)d_in[3];
  const float* b_out = (const float*)d_in[4];
  float* out = (float*)d_out;

  char* ws = (char*)d_ws;
  unsigned short* qkv_bf  = (unsigned short*)ws;                 ws += (size_t)M_ * QKV_LD * 2;
  unsigned short* attn_bf = (unsigned short*)ws;                 ws += (size_t)M_ * D_ * 2;
  unsigned short* x_bf    = (unsigned short*)ws;                 ws += (size_t)M_ * D_ * 2;
  unsigned short* wqkvT   = (unsigned short*)ws;                 ws += (size_t)QKV_LD * D_ * 2;
  unsigned short* woutT   = (unsigned short*)ws;

  dim3 blk(256);
  conv_bf16<<<(M_ * D_ / 4 + 255) / 256, blk, 0, stream>>>(x, x_bf, M_ * D_ / 4);
  transpose_bf16<<<dim3(QKV_LD / 32, D_ / 32), blk, 0, stream>>>(W_qkv, wqkvT, D_, QKV_LD);
  transpose_bf16<<<dim3(D_ / 32, D_ / 32), blk, 0, stream>>>(W_out, woutT, D_, D_);
  gemm_bf16_tn<unsigned short><<<dim3(QKV_LD / 128, M_ / 128), blk, 0, stream>>>(
      x_bf, wqkvT, b_qkv, qkv_bf, QKV_LD, D_);
  // balanced causal pairing with shared K/V staging: block x handles q-tiles x and 31-x
  attn_fwd_mfma<<<dim3(S_ / 64 / 2, B_ * H_), blk, 0, stream>>>(qkv_bf, attn_bf);
  gemm_bf16_tn<float><<<dim3(D_ / 128, M_ / 128), blk, 0, stream>>>(
      attn_bf, woutT, b_out, out, D_, D_);
}

// Round 8
// 169.758 us; speedup vs baseline: 1.0884x; 1.0884x over previous
//
#include <hip/hip_runtime.h>
#include <hip/hip_bf16.h>

#define B_  2
#define S_  2048
#define D_  1024
#define H_  16
#define DH_ 64
#define M_  (B_ * S_)       // 4096
#define QKV_LD (3 * D_)     // 3072

typedef __bf16 bf16x8 __attribute__((ext_vector_type(8)));
typedef float  f32x4  __attribute__((ext_vector_type(4)));
typedef unsigned short us4 __attribute__((ext_vector_type(4)));
typedef unsigned short us8 __attribute__((ext_vector_type(8)));

__device__ inline unsigned short f2bf(float f) {
  union { __bf16 h; unsigned short u; } cv; cv.h = (__bf16)f; return cv.u;
}
__device__ inline float bf2f(unsigned short u) {
  union { unsigned int i; float f; } cv; cv.i = ((unsigned int)u) << 16; return cv.f;
}
// typed stores: bf16 does the BIT conversion (round-3 bug: (unsigned short)v
// was an int conversion -> output was all-zero)
__device__ inline void cstore(float* p, float v) { *p = v; }
__device__ inline void cstore(unsigned short* p, float v) { *p = f2bf(v); }

__device__ inline void gload_lds16(const void* g, void* lds) {
  __builtin_amdgcn_global_load_lds(
      (const __attribute__((address_space(1))) unsigned int*)g,
      (__attribute__((address_space(3))) unsigned int*)lds, 16, 0, 0);
}

// ---------------- prep: fp32 -> bf16 (row-major copy) ----------------
__global__ __launch_bounds__(256) void conv_bf16(const float* __restrict__ in,
                                                 unsigned short* __restrict__ out, int n4) {
  int i = blockIdx.x * 256 + threadIdx.x;
  if (i >= n4) return;
  float4 v = ((const float4*)in)[i];
  us4 p = { f2bf(v.x), f2bf(v.y), f2bf(v.z), f2bf(v.w) };
  ((us4*)out)[i] = p;
}

// ---------------- prep: fp32 [K][N] -> bf16 [N][K] transpose ----------------
__global__ __launch_bounds__(256) void transpose_bf16(const float* __restrict__ W,
                                                      unsigned short* __restrict__ Wt,
                                                      int K, int N) {
  __shared__ float tile[32][33];
  const int t = threadIdx.x, tx = t & 31, ty = t >> 5;  // ty 0..7
  const int c0 = blockIdx.x * 32, r0 = blockIdx.y * 32;
  #pragma unroll
  for (int i = 0; i < 4; ++i)
    tile[ty + 8 * i][tx] = W[(size_t)(r0 + ty + 8 * i) * N + c0 + tx];
  __syncthreads();
  #pragma unroll
  for (int i = 0; i < 4; ++i)
    Wt[(size_t)(c0 + ty + 8 * i) * K + r0 + tx] = f2bf(tile[tx][ty + 8 * i]);
}

// ---------------- bf16 MFMA GEMM (m97 structure) ----------------
// C[M,N] = A[M,K] @ Bt[N,K]^T + bias.  128x128 tile, BK=32, 4 waves.
template<typename CT>
__global__ __launch_bounds__(256) void gemm_bf16_tn(
    const unsigned short* __restrict__ A,   // [M][K] bf16
    const unsigned short* __restrict__ Bt,  // [N][K] bf16
    const float* __restrict__ bias,
    CT* __restrict__ C, int N, int K) {
  __shared__ __align__(16) unsigned short smA[128 * 32];
  __shared__ __align__(16) unsigned short smB[128 * 32];
  const int t = threadIdx.x;
  const int w = t >> 6, l = t & 63;
  const int lg = l >> 4, lr = l & 15;
  const int row0 = blockIdx.y * 128, col0 = blockIdx.x * 128;
  const int wm = (w >> 1) * 64, wn = (w & 1) * 64;

  f32x4 acc[4][4] = {};

  for (int k0 = 0; k0 < K; k0 += 32) {
    __syncthreads();  // previous iteration's fragment reads complete
    #pragma unroll
    for (int i = 0; i < 2; ++i) {
      const int inst = 2 * w + i;
      const int r = inst * 16 + (l >> 2);
      const int cb = (l & 3) * 8;  // k-chunk of 8 bf16
      gload_lds16(A  + (size_t)(row0 + r) * K + k0 + cb, &smA[inst * 512]);
      gload_lds16(Bt + (size_t)(col0 + r) * K + k0 + cb, &smB[inst * 512]);
    }
    __syncthreads();  // waits vmcnt(0): tiles resident

    bf16x8 af[4], bfr[4];
    #pragma unroll
    for (int m = 0; m < 4; ++m)
      af[m] = *(const bf16x8*)&smA[(wm + m * 16 + lr) * 32 + lg * 8];
    #pragma unroll
    for (int n = 0; n < 4; ++n)
      bfr[n] = *(const bf16x8*)&smB[(wn + n * 16 + lr) * 32 + lg * 8];
    #pragma unroll
    for (int m = 0; m < 4; ++m)
      #pragma unroll
      for (int n = 0; n < 4; ++n)
        acc[m][n] = __builtin_amdgcn_mfma_f32_16x16x32_bf16(af[m], bfr[n], acc[m][n], 0, 0, 0);
  }

  #pragma unroll
  for (int m = 0; m < 4; ++m) {
    #pragma unroll
    for (int n = 0; n < 4; ++n) {
      const int col = col0 + wn + n * 16 + lr;
      const float bv = bias[col];
      #pragma unroll
      for (int r = 0; r < 4; ++r) {
        const int row = row0 + wm + m * 16 + lg * 4 + r;
        cstore(&C[(size_t)row * N + col], acc[m][n][r] + bv);
      }
    }
  }
}

// ---------------- Causal flash attention, bf16 MFMA ----------------
// Balanced pairing at 32-row granularity: block y processes q-tiles y and
// 63-y sequentially; ntiles_lo + ntiles_hi == 33 for every y. 2 waves x
// 16 q-rows per phase; KVBLK=64; LDS double-buffered K/V, T14 async
// staging, 1 barrier/tile. 1024 blocks -> 4 blocks/CU = 16 waves/CU.
__global__ __launch_bounds__(128, 4) void attn_fwd_mfma(
    const unsigned short* __restrict__ qkv, unsigned short* __restrict__ attn_out) {
  const int bh = blockIdx.y;
  const int b = bh / H_, h = bh % H_;
  const unsigned short* base = qkv + (size_t)b * S_ * QKV_LD;

  __shared__ __align__(16) char smK[2][64 * 128];  // K tile [k][d], XOR-swizzled
  __shared__ __align__(16) char smV[2][64 * 128];  // V^T tile [d][k]
  __shared__ __align__(16) char smP[32 * 128];     // P [q][k], wave-private rows

  const int t  = threadIdx.x;      // 0..127
  const int w  = t >> 6;           // 0..1
  const int l  = t & 63;
  const int lg = l >> 4;
  const int lr = l & 15;
  const int yp = blockIdx.x;       // lo q-tile index (32-row tiles)

  const unsigned short* kbase = base + D_ + h * DH_;
  const unsigned short* vbase = base + 2 * D_ + h * DH_;

  // staging registers (T14 async split: issue early, LDS-write late)
  us8 kreg[4], vreg[4];
  const int kp  = (t & 31) * 2;    // V: pair of k-columns
  const int vdb = (t >> 5) * 8;    // V: first d-octet (0/8/16/24); also +32

  auto issue_loads = [&](int k0) {
    #pragma unroll
    for (int it = 0; it < 4; ++it) {
      int idx = t + it * 128;
      int r = idx >> 3, c = idx & 7;
      kreg[it] = *(const us8*)(kbase + (size_t)(k0 + r) * QKV_LD + c * 8);
    }
    vreg[0] = *(const us8*)(vbase + (size_t)(k0 + kp) * QKV_LD + vdb);
    vreg[1] = *(const us8*)(vbase + (size_t)(k0 + kp + 1) * QKV_LD + vdb);
    vreg[2] = *(const us8*)(vbase + (size_t)(k0 + kp) * QKV_LD + vdb + 32);
    vreg[3] = *(const us8*)(vbase + (size_t)(k0 + kp + 1) * QKV_LD + vdb + 32);
  };
  auto write_lds = [&](int buf) {
    #pragma unroll
    for (int it = 0; it < 4; ++it) {
      int idx = t + it * 128;
      int r = idx >> 3, c = idx & 7;
      *(us8*)(smK[buf] + r * 128 + ((c * 16) ^ ((r & 7) << 4))) = kreg[it];
    }
    #pragma unroll
    for (int j = 0; j < 8; ++j) {
      int row0 = vdb + j;
      unsigned int pv0 = (unsigned int)vreg[0][j] | ((unsigned int)vreg[1][j] << 16);
      *(unsigned int*)(smV[buf] + row0 * 128 + ((2 * kp) ^ ((row0 & 7) << 4))) = pv0;
      int row1 = vdb + 32 + j;
      unsigned int pv1 = (unsigned int)vreg[2][j] | ((unsigned int)vreg[3][j] << 16);
      *(unsigned int*)(smV[buf] + row1 * 128 + ((2 * kp) ^ ((row1 & 7) << 4))) = pv1;
    }
  };

  #pragma unroll 1
  for (int sel = 0; sel < 2; ++sel) {
    const int qt = sel ? (63 - yp) : yp;
    const int q0 = qt * 32;
    const int qw0 = q0 + w * 16;   // wave owns rows qw0..qw0+15
    // lo: tiles 0..(yp>>1);  hi: tiles 0..floor((2047-32*yp)/64). Sum == 33.
    const int ntiles = sel ? (((2047 - 32 * yp) >> 6) + 1) : ((yp >> 1) + 1);

    // ---- Q fragments (pre-scaled by 1/8) ----
    bf16x8 qf[2];
    {
      const unsigned short* qp = base + (size_t)(qw0 + lr) * QKV_LD + h * DH_ + 8 * lg;
      #pragma unroll
      for (int ks = 0; ks < 2; ++ks) {
        us8 qv = *(const us8*)(qp + 32 * ks);
        #pragma unroll
        for (int e = 0; e < 8; ++e) qf[ks][e] = (__bf16)(bf2f(qv[e]) * 0.125f);
      }
    }

    float mrun[4], lrun[4];
    f32x4 acc_o[4] = {};
    #pragma unroll
    for (int r = 0; r < 4; ++r) { mrun[r] = -1e30f; lrun[r] = 0.f; }

    issue_loads(0);
    write_lds(0);
    __syncthreads();

    for (int kti = 0; kti < ntiles; ++kti) {
      const int k0 = kti * 64;
      const int cur = kti & 1;

      if (kti + 1 < ntiles) issue_loads((kti + 1) * 64);

      // ---- QK^T ----
      f32x4 sc[4] = {};
      #pragma unroll
      for (int kt = 0; kt < 4; ++kt)
        #pragma unroll
        for (int ks = 0; ks < 2; ++ks) {
          int row = kt * 16 + lr;
          bf16x8 kb = *(const bf16x8*)(smK[cur] + row * 128 +
                                       (((ks * 64) + 16 * lg) ^ ((row & 7) << 4)));
          sc[kt] = __builtin_amdgcn_mfma_f32_16x16x32_bf16(qf[ks], kb, sc[kt], 0, 0, 0);
        }

      // ---- causal mask (only the last tile of each phase touches diagonal) ----
      if (kti == ntiles - 1) {
        #pragma unroll
        for (int kt = 0; kt < 4; ++kt) {
          int kc = k0 + kt * 16 + lr;
          #pragma unroll
          for (int r = 0; r < 4; ++r)
            if (kc > qw0 + lg * 4 + r) sc[kt][r] = -1e30f;
        }
      }

      // ---- online softmax (rows across 16-lane groups) ----
      float mnew[4], alpha[4];
      #pragma unroll
      for (int r = 0; r < 4; ++r) {
        float v = fmaxf(fmaxf(sc[0][r], sc[1][r]), fmaxf(sc[2][r], sc[3][r]));
        #pragma unroll
        for (int off = 1; off < 16; off <<= 1) v = fmaxf(v, __shfl_xor(v, off));
        mnew[r] = fmaxf(mrun[r], v);
        alpha[r] = __expf(mrun[r] - mnew[r]);
        mrun[r] = mnew[r];
      }
      #pragma unroll
      for (int r = 0; r < 4; ++r) {
        float s = 0.f;
        #pragma unroll
        for (int kt = 0; kt < 4; ++kt) {
          float p = __expf(sc[kt][r] - mnew[r]);
          sc[kt][r] = p;
          s += p;
        }
        #pragma unroll
        for (int off = 1; off < 16; off <<= 1) s += __shfl_xor(s, off);
        lrun[r] = lrun[r] * alpha[r] + s;
      }

      // ---- write P (wave-private rows), rescale O ----
      #pragma unroll
      for (int kt = 0; kt < 4; ++kt)
        #pragma unroll
        for (int r = 0; r < 4; ++r) {
          int row = w * 16 + lg * 4 + r;
          *(unsigned short*)(smP + row * 128 + ((2 * (kt * 16 + lr)) ^ ((row & 7) << 4))) =
              f2bf(sc[kt][r]);
        }
      #pragma unroll
      for (int dt = 0; dt < 4; ++dt)
        #pragma unroll
        for (int r = 0; r < 4; ++r) acc_o[dt][r] *= alpha[r];

      // ---- PV ----
      bf16x8 pa[2];
      #pragma unroll
      for (int ks = 0; ks < 2; ++ks) {
        int row = w * 16 + lr;
        pa[ks] = *(const bf16x8*)(smP + row * 128 +
                                  (((ks * 64) + 16 * lg) ^ ((lr & 7) << 4)));
      }
      #pragma unroll
      for (int dt = 0; dt < 4; ++dt)
        #pragma unroll
        for (int ks = 0; ks < 2; ++ks) {
          int row = dt * 16 + lr;
          bf16x8 vb = *(const bf16x8*)(smV[cur] + row * 128 +
                                       (((ks * 64) + 16 * lg) ^ ((row & 7) << 4)));
          acc_o[dt] = __builtin_amdgcn_mfma_f32_16x16x32_bf16(pa[ks], vb, acc_o[dt], 0, 0, 0);
        }

      if (kti + 1 < ntiles) write_lds(cur ^ 1);  // buf cur^1 free since last barrier
      __syncthreads();
    }

    // ---- normalize and write out (bf16) ----
    float inv[4];
    #pragma unroll
    for (int r = 0; r < 4; ++r) inv[r] = 1.0f / lrun[r];
    #pragma unroll
    for (int dt = 0; dt < 4; ++dt)
      #pragma unroll
      for (int r = 0; r < 4; ++r)
        attn_out[(size_t)(b * S_ + qw0 + lg * 4 + r) * D_ + h * DH_ + dt * 16 + lr] =
            f2bf(acc_o[dt][r] * inv[r]);
  }
}

extern "C" void kernel_launch(void* const* d_in, const int* in_sizes, int n_in,
                              void* d_out, int out_size, void* d_ws, size_t ws_size,
                              hipStream_t stream) {
  const float* x     = (const float*)d_in[0];
  const float* W_qkv = (const float*)d_in[1];
  const float* b_qkv = (const float*)d_in[2];
  const float* W_out = (const float*)d_in[3];
  const float* b_out = (const float*)d_in[4];
  float* out = (float*)d_out;

  char* ws = (char*)d_ws;
  unsigned short* qkv_bf  = (unsigned short*)ws;                 ws += (size_t)M_ * QKV_LD * 2;
  unsigned short* attn_bf = (unsigned short*)ws;                 ws += (size_t)M_ * D_ * 2;
  unsigned short* x_bf    = (unsigned short*)ws;                 ws += (size_t)M_ * D_ * 2;
  unsigned short* wqkvT   = (unsigned short*)ws;                 ws += (size_t)QKV_LD * D_ * 2;
  unsigned short* woutT   = (unsigned short*)ws;

  dim3 blk(256);
  conv_bf16<<<(M_ * D_ / 4 + 255) / 256, blk, 0, stream>>>(x, x_bf, M_ * D_ / 4);
  transpose_bf16<<<dim3(QKV_LD / 32, D_ / 32), blk, 0, stream>>>(W_qkv, wqkvT, D_, QKV_LD);
  transpose_bf16<<<dim3(D_ / 32, D_ / 32), blk, 0, stream>>>(W_out, woutT, D_, D_);
  gemm_bf16_tn<unsigned short><<<dim3(QKV_LD / 128, M_ / 128), blk, 0, stream>>>(
      x_bf, wqkvT, b_qkv, qkv_bf, QKV_LD, D_);
  // balanced causal pairing at 32-row granularity: block y handles q-tiles y and 63-y
  attn_fwd_mfma<<<dim3(S_ / 32 / 2, B_ * H_), dim3(128), 0, stream>>>(qkv_bf, attn_bf);
  gemm_bf16_tn<float><<<dim3(D_ / 128, M_ / 128), blk, 0, stream>>>(
      attn_bf, woutT, b_out, out, D_, D_);
}

// Round 9
// 147.495 us; speedup vs baseline: 1.2526x; 1.1509x over previous
//
#include <hip/hip_runtime.h>
#include <hip/hip_bf16.h>

#define B_  2
#define S_  2048
#define D_  1024
#define H_  16
#define DH_ 64
#define M_  (B_ * S_)       // 4096
#define QKV_LD (3 * D_)     // 3072

typedef __bf16 bf16x8 __attribute__((ext_vector_type(8)));
typedef float  f32x4  __attribute__((ext_vector_type(4)));
typedef unsigned short us4 __attribute__((ext_vector_type(4)));
typedef unsigned short us8 __attribute__((ext_vector_type(8)));

__device__ inline unsigned short f2bf(float f) {
  union { __bf16 h; unsigned short u; } cv; cv.h = (__bf16)f; return cv.u;
}
__device__ inline float bf2f(unsigned short u) {
  union { unsigned int i; float f; } cv; cv.i = ((unsigned int)u) << 16; return cv.f;
}
// typed stores: bf16 does the BIT conversion (round-3 bug: (unsigned short)v
// was an int conversion -> output was all-zero)
__device__ inline void cstore(float* p, float v) { *p = v; }
__device__ inline void cstore(unsigned short* p, float v) { *p = f2bf(v); }

__device__ inline void gload_lds16(const void* g, void* lds) {
  __builtin_amdgcn_global_load_lds(
      (const __attribute__((address_space(1))) unsigned int*)g,
      (__attribute__((address_space(3))) unsigned int*)lds, 16, 0, 0);
}

// ---------------- prep: fp32 -> bf16 (row-major copy) ----------------
__global__ __launch_bounds__(256) void conv_bf16(const float* __restrict__ in,
                                                 unsigned short* __restrict__ out, int n4) {
  int i = blockIdx.x * 256 + threadIdx.x;
  if (i >= n4) return;
  float4 v = ((const float4*)in)[i];
  us4 p = { f2bf(v.x), f2bf(v.y), f2bf(v.z), f2bf(v.w) };
  ((us4*)out)[i] = p;
}

// ---------------- prep: fp32 [K][N] -> bf16 [N][K] transpose ----------------
__global__ __launch_bounds__(256) void transpose_bf16(const float* __restrict__ W,
                                                      unsigned short* __restrict__ Wt,
                                                      int K, int N) {
  __shared__ float tile[32][33];
  const int t = threadIdx.x, tx = t & 31, ty = t >> 5;  // ty 0..7
  const int c0 = blockIdx.x * 32, r0 = blockIdx.y * 32;
  #pragma unroll
  for (int i = 0; i < 4; ++i)
    tile[ty + 8 * i][tx] = W[(size_t)(r0 + ty + 8 * i) * N + c0 + tx];
  __syncthreads();
  #pragma unroll
  for (int i = 0; i < 4; ++i)
    Wt[(size_t)(c0 + ty + 8 * i) * K + r0 + tx] = f2bf(tile[tx][ty + 8 * i]);
}

// ---------------- bf16 MFMA GEMM (m97 structure) ----------------
// C[M,N] = A[M,K] @ Bt[N,K]^T + bias.  128x128 tile, BK=32, 4 waves.
template<typename CT>
__global__ __launch_bounds__(256) void gemm_bf16_tn(
    const unsigned short* __restrict__ A,   // [M][K] bf16
    const unsigned short* __restrict__ Bt,  // [N][K] bf16
    const float* __restrict__ bias,
    CT* __restrict__ C, int N, int K) {
  __shared__ __align__(16) unsigned short smA[128 * 32];
  __shared__ __align__(16) unsigned short smB[128 * 32];
  const int t = threadIdx.x;
  const int w = t >> 6, l = t & 63;
  const int lg = l >> 4, lr = l & 15;
  const int row0 = blockIdx.y * 128, col0 = blockIdx.x * 128;
  const int wm = (w >> 1) * 64, wn = (w & 1) * 64;

  f32x4 acc[4][4] = {};

  for (int k0 = 0; k0 < K; k0 += 32) {
    __syncthreads();  // previous iteration's fragment reads complete
    #pragma unroll
    for (int i = 0; i < 2; ++i) {
      const int inst = 2 * w + i;
      const int r = inst * 16 + (l >> 2);
      const int cb = (l & 3) * 8;  // k-chunk of 8 bf16
      gload_lds16(A  + (size_t)(row0 + r) * K + k0 + cb, &smA[inst * 512]);
      gload_lds16(Bt + (size_t)(col0 + r) * K + k0 + cb, &smB[inst * 512]);
    }
    __syncthreads();  // waits vmcnt(0): tiles resident

    bf16x8 af[4], bfr[4];
    #pragma unroll
    for (int m = 0; m < 4; ++m)
      af[m] = *(const bf16x8*)&smA[(wm + m * 16 + lr) * 32 + lg * 8];
    #pragma unroll
    for (int n = 0; n < 4; ++n)
      bfr[n] = *(const bf16x8*)&smB[(wn + n * 16 + lr) * 32 + lg * 8];
    #pragma unroll
    for (int m = 0; m < 4; ++m)
      #pragma unroll
      for (int n = 0; n < 4; ++n)
        acc[m][n] = __builtin_amdgcn_mfma_f32_16x16x32_bf16(af[m], bfr[n], acc[m][n], 0, 0, 0);
  }

  #pragma unroll
  for (int m = 0; m < 4; ++m) {
    #pragma unroll
    for (int n = 0; n < 4; ++n) {
      const int col = col0 + wn + n * 16 + lr;
      const float bv = bias[col];
      #pragma unroll
      for (int r = 0; r < 4; ++r) {
        const int row = row0 + wm + m * 16 + lg * 4 + r;
        cstore(&C[(size_t)row * N + col], acc[m][n][r] + bv);
      }
    }
  }
}

// ---------------- Causal flash attention, bf16 MFMA ----------------
// Round-6 structure (best measured: 83 us) + XCD-aware work remap.
// 512 blocks; linear bid & 7 selects XCD (HW round-robin), so each XCD's
// 64 blocks are remapped to own 4 whole (b,h) pairs x 16 balanced q-pairs.
// K/V per bh (0.5 MB) then stays in that XCD's L2 across all its blocks
// (round-8 diagnosis: without this, all 8 XCDs re-fetch every bh's K/V
// from HBM -> 118 MB FETCH). Balanced pairing: work unit x handles q-tiles
// x and 31-x sequentially (33 k-tile units each). 4 waves x 16 q-rows;
// KVBLK=64; LDS dbuf K/V; T14 async staging; 1 barrier/tile.
__global__ __launch_bounds__(256) void attn_fwd_mfma(
    const unsigned short* __restrict__ qkv, unsigned short* __restrict__ attn_out) {
  const int bid = blockIdx.x + gridDim.x * blockIdx.y;  // 0..511
  const int xcd = bid & 7;
  const int li  = bid >> 3;          // 0..63 within XCD
  const int bh  = xcd * 4 + (li >> 4);  // 4 bh per XCD
  const int x   = li & 15;           // balanced q-pair index 0..15
  const int b = bh / H_, h = bh % H_;
  const unsigned short* base = qkv + (size_t)b * S_ * QKV_LD;

  __shared__ __align__(16) char smK[2][64 * 128];  // K tile [k][d], XOR-swizzled
  __shared__ __align__(16) char smV[2][64 * 128];  // V^T tile [d][k]
  __shared__ __align__(16) char smP[64 * 128];     // P [q][k], wave-private rows

  const int t  = threadIdx.x;
  const int w  = t >> 6;
  const int l  = t & 63;
  const int lg = l >> 4;
  const int lr = l & 15;

  const unsigned short* kbase = base + D_ + h * DH_;
  const unsigned short* vbase = base + 2 * D_ + h * DH_;

  // staging registers (T14 async split: issue early, LDS-write late)
  us8 kreg[2], vreg[2];
  const int kp  = (t & 31) * 2;    // V: pair of k-columns
  const int vdb = (t >> 5) * 8;    // V: 8 d-rows

  auto issue_loads = [&](int k0) {
    #pragma unroll
    for (int it = 0; it < 2; ++it) {
      int idx = t + it * 256;
      int r = idx >> 3, c = idx & 7;
      kreg[it] = *(const us8*)(kbase + (size_t)(k0 + r) * QKV_LD + c * 8);
    }
    vreg[0] = *(const us8*)(vbase + (size_t)(k0 + kp) * QKV_LD + vdb);
    vreg[1] = *(const us8*)(vbase + (size_t)(k0 + kp + 1) * QKV_LD + vdb);
  };
  auto write_lds = [&](int buf) {
    #pragma unroll
    for (int it = 0; it < 2; ++it) {
      int idx = t + it * 256;
      int r = idx >> 3, c = idx & 7;
      *(us8*)(smK[buf] + r * 128 + ((c * 16) ^ ((r & 7) << 4))) = kreg[it];
    }
    #pragma unroll
    for (int j = 0; j < 8; ++j) {
      int row = vdb + j;
      unsigned int pv = (unsigned int)vreg[0][j] | ((unsigned int)vreg[1][j] << 16);
      *(unsigned int*)(smV[buf] + row * 128 + ((2 * kp) ^ ((row & 7) << 4))) = pv;
    }
  };

  #pragma unroll 1
  for (int sel = 0; sel < 2; ++sel) {
    const int qt = sel ? (31 - x) : x;
    const int q0 = qt * 64;
    const int qw0 = q0 + w * 16;   // wave owns rows qw0..qw0+15

    // ---- Q fragments (pre-scaled by 1/8) ----
    bf16x8 qf[2];
    {
      const unsigned short* qp = base + (size_t)(qw0 + lr) * QKV_LD + h * DH_ + 8 * lg;
      #pragma unroll
      for (int ks = 0; ks < 2; ++ks) {
        us8 qv = *(const us8*)(qp + 32 * ks);
        #pragma unroll
        for (int e = 0; e < 8; ++e) qf[ks][e] = (__bf16)(bf2f(qv[e]) * 0.125f);
      }
    }

    float mrun[4], lrun[4];
    f32x4 acc_o[4] = {};
    #pragma unroll
    for (int r = 0; r < 4; ++r) { mrun[r] = -1e30f; lrun[r] = 0.f; }

    const int ntiles = qt + 1;  // k tiles covering k <= q0+63
    issue_loads(0);
    write_lds(0);
    __syncthreads();

    for (int kti = 0; kti < ntiles; ++kti) {
      const int k0 = kti * 64;
      const int cur = kti & 1;

      if (kti + 1 < ntiles) issue_loads((kti + 1) * 64);

      if (k0 <= qw0 + 15) {  // wave not fully masked
        // ---- QK^T ----
        f32x4 sc[4] = {};
        #pragma unroll
        for (int kt = 0; kt < 4; ++kt)
          #pragma unroll
          for (int ks = 0; ks < 2; ++ks) {
            int row = kt * 16 + lr;
            bf16x8 kb = *(const bf16x8*)(smK[cur] + row * 128 +
                                         (((ks * 64) + 16 * lg) ^ ((row & 7) << 4)));
            sc[kt] = __builtin_amdgcn_mfma_f32_16x16x32_bf16(qf[ks], kb, sc[kt], 0, 0, 0);
          }

        // ---- causal mask near diagonal ----
        if (k0 + 63 > qw0) {
          #pragma unroll
          for (int kt = 0; kt < 4; ++kt) {
            int kc = k0 + kt * 16 + lr;
            #pragma unroll
            for (int r = 0; r < 4; ++r)
              if (kc > qw0 + lg * 4 + r) sc[kt][r] = -1e30f;
          }
        }

        // ---- online softmax (rows across 16-lane groups) ----
        float mnew[4], alpha[4];
        #pragma unroll
        for (int r = 0; r < 4; ++r) {
          float v = fmaxf(fmaxf(sc[0][r], sc[1][r]), fmaxf(sc[2][r], sc[3][r]));
          #pragma unroll
          for (int off = 1; off < 16; off <<= 1) v = fmaxf(v, __shfl_xor(v, off));
          mnew[r] = fmaxf(mrun[r], v);
          alpha[r] = __expf(mrun[r] - mnew[r]);
          mrun[r] = mnew[r];
        }
        #pragma unroll
        for (int r = 0; r < 4; ++r) {
          float s = 0.f;
          #pragma unroll
          for (int kt = 0; kt < 4; ++kt) {
            float p = __expf(sc[kt][r] - mnew[r]);
            sc[kt][r] = p;
            s += p;
          }
          #pragma unroll
          for (int off = 1; off < 16; off <<= 1) s += __shfl_xor(s, off);
          lrun[r] = lrun[r] * alpha[r] + s;
        }

        // ---- write P (wave-private rows), rescale O ----
        #pragma unroll
        for (int kt = 0; kt < 4; ++kt)
          #pragma unroll
          for (int r = 0; r < 4; ++r) {
            int row = w * 16 + lg * 4 + r;
            *(unsigned short*)(smP + row * 128 + ((2 * (kt * 16 + lr)) ^ ((row & 7) << 4))) =
                f2bf(sc[kt][r]);
          }
        #pragma unroll
        for (int dt = 0; dt < 4; ++dt)
          #pragma unroll
          for (int r = 0; r < 4; ++r) acc_o[dt][r] *= alpha[r];

        // ---- PV ----
        bf16x8 pa[2];
        #pragma unroll
        for (int ks = 0; ks < 2; ++ks) {
          int row = w * 16 + lr;
          pa[ks] = *(const bf16x8*)(smP + row * 128 +
                                    (((ks * 64) + 16 * lg) ^ ((lr & 7) << 4)));
        }
        #pragma unroll
        for (int dt = 0; dt < 4; ++dt)
          #pragma unroll
          for (int ks = 0; ks < 2; ++ks) {
            int row = dt * 16 + lr;
            bf16x8 vb = *(const bf16x8*)(smV[cur] + row * 128 +
                                         (((ks * 64) + 16 * lg) ^ ((row & 7) << 4)));
            acc_o[dt] = __builtin_amdgcn_mfma_f32_16x16x32_bf16(pa[ks], vb, acc_o[dt], 0, 0, 0);
          }
      }

      if (kti + 1 < ntiles) write_lds(cur ^ 1);  // buf cur^1 free since last barrier
      __syncthreads();
    }

    // ---- normalize and write out (bf16) ----
    float inv[4];
    #pragma unroll
    for (int r = 0; r < 4; ++r) inv[r] = 1.0f / lrun[r];
    #pragma unroll
    for (int dt = 0; dt < 4; ++dt)
      #pragma unroll
      for (int r = 0; r < 4; ++r)
        attn_out[(size_t)(b * S_ + qw0 + lg * 4 + r) * D_ + h * DH_ + dt * 16 + lr] =
            f2bf(acc_o[dt][r] * inv[r]);
  }
}

extern "C" void kernel_launch(void* const* d_in, const int* in_sizes, int n_in,
                              void* d_out, int out_size, void* d_ws, size_t ws_size,
                              hipStream_t stream) {
  const float* x     = (const float*)d_in[0];
  const float* W_qkv = (const float*)d_in[1];
  const float* b_qkv = (const float*)d_in[2];
  const float* W_out = (const float*)d_in[3];
  const float* b_out = (const float*)d_in[4];
  float* out = (float*)d_out;

  char* ws = (char*)d_ws;
  unsigned short* qkv_bf  = (unsigned short*)ws;                 ws += (size_t)M_ * QKV_LD * 2;
  unsigned short* attn_bf = (unsigned short*)ws;                 ws += (size_t)M_ * D_ * 2;
  unsigned short* x_bf    = (unsigned short*)ws;                 ws += (size_t)M_ * D_ * 2;
  unsigned short* wqkvT   = (unsigned short*)ws;                 ws += (size_t)QKV_LD * D_ * 2;
  unsigned short* woutT   = (unsigned short*)ws;

  dim3 blk(256);
  conv_bf16<<<(M_ * D_ / 4 + 255) / 256, blk, 0, stream>>>(x, x_bf, M_ * D_ / 4);
  transpose_bf16<<<dim3(QKV_LD / 32, D_ / 32), blk, 0, stream>>>(W_qkv, wqkvT, D_, QKV_LD);
  transpose_bf16<<<dim3(D_ / 32, D_ / 32), blk, 0, stream>>>(W_out, woutT, D_, D_);
  gemm_bf16_tn<unsigned short><<<dim3(QKV_LD / 128, M_ / 128), blk, 0, stream>>>(
      x_bf, wqkvT, b_qkv, qkv_bf, QKV_LD, D_);
  // balanced causal pairing + XCD-aware bh grouping (remap inside kernel)
  attn_fwd_mfma<<<dim3(S_ / 64 / 2, B_ * H_), blk, 0, stream>>>(qkv_bf, attn_bf);
  gemm_bf16_tn<float><<<dim3(D_ / 128, M_ / 128), blk, 0, stream>>>(
      attn_bf, woutT, b_out, out, D_, D_);
}